// Round 8
// baseline (300.879 us; speedup 1.0000x reference)
//
#include <hip/hip_runtime.h>
#include <hip/hip_bf16.h>

#define N_NODES 100000
#define N_EDGES 1600000
#define N_GRAPHS 512
#define NODE_DIM 64
#define GRAPH_DIM 16
#define HIDDEN 128
#define OUT_DIM 8

#define NBUCKETS 391      // ceil(N_NODES/256)
#define BIN_CAP 8192      // per-bucket bin capacity (avg 4092)
#define EPB 4096          // edges per binning block

__device__ __forceinline__ float bflo(unsigned u) { return __uint_as_float(u << 16); }
__device__ __forceinline__ float bfhi(unsigned u) { return __uint_as_float(u & 0xffff0000u); }

// ---------------- phase A: bin edges by dst>>8; entry = (src<<8)|(dst&255) ----------------

__global__ __launch_bounds__(256) void k_binplace(const int* __restrict__ src,
                                                  const int* __restrict__ dst,
                                                  int* __restrict__ gcur,
                                                  unsigned* __restrict__ bin) {
    __shared__ int cnt[NBUCKETS];
    __shared__ int base[NBUCKETS];
    int t = threadIdx.x;
    for (int i = t; i < NBUCKETS; i += 256) cnt[i] = 0;
    __syncthreads();
    int e0 = blockIdx.x * EPB;
#pragma unroll
    for (int k = 0; k < EPB / 256; k++) {
        int e = e0 + k * 256 + t;
        if (e < N_EDGES) atomicAdd(&cnt[dst[e] >> 8], 1);
    }
    __syncthreads();
    for (int i = t; i < NBUCKETS; i += 256) {
        int c = cnt[i];
        base[i] = (c > 0) ? atomicAdd(&gcur[i], c) : 0;
        cnt[i] = 0;
    }
    __syncthreads();
#pragma unroll
    for (int k = 0; k < EPB / 256; k++) {
        int e = e0 + k * 256 + t;
        if (e < N_EDGES) {
            int d = dst[e];
            int b = d >> 8;
            int p = atomicAdd(&cnt[b], 1);
            bin[(size_t)b * BIN_CAP + base[b] + p] = ((unsigned)src[e] << 8) | (unsigned)(d & 255);
        }
    }
}

// ---------------- phase B1: per-bucket degree count + dinv + block sum ----------------

__global__ __launch_bounds__(256) void k_degBf(const int* __restrict__ gcur,
                                               const unsigned* __restrict__ bin,
                                               int* __restrict__ degcnt,
                                               float* __restrict__ dinv,
                                               int* __restrict__ bsum) {
    __shared__ int cnt[256];
    int b = blockIdx.x, t = threadIdx.x;
    cnt[t] = 0;
    __syncthreads();
    int n = gcur[b];
    const unsigned* seg = bin + (size_t)b * BIN_CAP;
    for (int i = t; i < n; i += 256) atomicAdd(&cnt[seg[i] & 255u], 1);
    __syncthreads();
    int c = cnt[t];
    int node = b * 256 + t;
    if (node < N_NODES) {
        degcnt[node] = c;
        dinv[node] = rsqrtf((float)c + 1.0f);
    }
    __syncthreads();
    for (int o = 128; o > 0; o >>= 1) {
        if (t < o) cnt[t] += cnt[t + o];
        __syncthreads();
    }
    if (t == 0) bsum[b] = cnt[0];
}

// ---------------- exclusive scan of bsum -> bofs (one 512-thread block) ----------------

__global__ __launch_bounds__(512) void k_scanb(const int* __restrict__ bsum,
                                               int* __restrict__ bofs) {
    __shared__ int s[512];
    int t = threadIdx.x;
    int v = (t < NBUCKETS) ? bsum[t] : 0;
    s[t] = v;
    __syncthreads();
    for (int o = 1; o < 512; o <<= 1) {
        int u = (t >= o) ? s[t - o] : 0;
        __syncthreads();
        s[t] += u;
        __syncthreads();
    }
    if (t < NBUCKETS) bofs[t] = s[t] - v;
}

// ---------------- phase B2: fused rowstart + CSR fill (int2 {src, w}); zeroes gt_sum ----------------

__global__ __launch_bounds__(256) void k_rowfill(const int* __restrict__ degcnt,
                                                 const int* __restrict__ bofs,
                                                 const int* __restrict__ gcur,
                                                 const unsigned* __restrict__ bin,
                                                 const float* __restrict__ dinv,
                                                 int* __restrict__ row_start,
                                                 int2* __restrict__ csre,
                                                 float* __restrict__ gt_sum) {
    __shared__ int sc[256];
    __shared__ int rsl[256];
    __shared__ int cnt[256];
    __shared__ float dl[256];
    int b = blockIdx.x, t = threadIdx.x;
    if (b < 32) gt_sum[b * 256 + t] = 0.0f;
    int node = b * 256 + t;
    int v = (node < N_NODES) ? degcnt[node] : 0;
    sc[t] = v;
    __syncthreads();
    for (int o = 1; o < 256; o <<= 1) {
        int u = (t >= o) ? sc[t - o] : 0;
        __syncthreads();
        sc[t] += u;
        __syncthreads();
    }
    int rs = bofs[b] + sc[t] - v;  // exclusive
    if (node < N_NODES) row_start[node] = rs;
    rsl[t] = rs;
    cnt[t] = 0;
    dl[t] = rsqrtf((float)v + 1.0f);
    __syncthreads();
    int n = gcur[b];
    const unsigned* seg = bin + (size_t)b * BIN_CAP;
    for (int i = t; i < n; i += 256) {
        unsigned e = seg[i];
        int dlidx = (int)(e & 255u);
        int s = (int)(e >> 8);
        int pos = rsl[dlidx] + atomicAdd(&cnt[dlidx], 1);
        csre[pos] = make_int2(s, __float_as_int(dinv[s] * dl[dlidx]));
    }
}

// ---------------- fused: pack x[:, :64] to bf16 + graph feature pooling ----------------

__global__ __launch_bounds__(256) void k_packstat(const float* __restrict__ x,
                                                  const int* __restrict__ batch,
                                                  ushort* __restrict__ xb,
                                                  float* __restrict__ gt_sum) {
    int t = threadIdx.x;
    int i0 = blockIdx.x * 64;
    for (int idx = t; idx < 64 * 32; idx += 256) {
        int node = i0 + (idx >> 5);
        if (node < N_NODES) {
            int c2 = idx & 31;
            float2 v = *(const float2*)&x[(size_t)node * 80 + c2 * 2];
            __hip_bfloat16 lo = __float2bfloat16(v.x);
            __hip_bfloat16 hi = __float2bfloat16(v.y);
            ushort2 pv = make_ushort2(*(ushort*)&lo, *(ushort*)&hi);
            ((ushort2*)xb)[(size_t)node * 32 + c2] = pv;
        }
    }
    int c = t & 15, sub = t >> 4;  // 16 subs x 16 channels
    int iend = min(i0 + 64, N_NODES);
    float acc = 0.0f;
    int g = -1;
    for (int i = i0 + sub; i < iend; i += 16) {
        int bi = batch[i];
        if (bi != g) {
            if (g >= 0) atomicAdd(&gt_sum[g * GRAPH_DIM + c], acc);
            acc = 0.0f; g = bi;
        }
        acc += x[(size_t)i * 80 + NODE_DIM + c];
    }
    if (g >= 0) atomicAdd(&gt_sum[g * GRAPH_DIM + c], acc);
}

// ---- fused conv1: gather (A_hat x64, edge-pair half-wave) + GEMM -> h1 bf16; zeroes gsum2 ----

__global__ __launch_bounds__(512) void k_conv1(const int2* __restrict__ csre,
                                               const int* __restrict__ row_start,
                                               const float* __restrict__ dinv,
                                               const unsigned* __restrict__ xb32,
                                               const float* __restrict__ W,
                                               const float* __restrict__ bias,
                                               ushort* __restrict__ C,
                                               float* __restrict__ gsum2) {
    __shared__ float zs[8][64];
    int t = threadIdx.x;
    if (blockIdx.x < 128) gsum2[blockIdx.x * 512 + t] = 0.0f;
    int wv = t >> 6;        // wave 0..7, one node per wave
    int lane = t & 63;
    int half = lane >> 5;   // 0 | 1
    int l5 = lane & 31;
    int node = blockIdx.x * 8 + wv;
    int rs = row_start[node];
    int re = (node == N_NODES - 1) ? N_EDGES : row_start[node + 1];
    float2 a0 = {0.f,0.f}, a1 = {0.f,0.f}, a2 = {0.f,0.f}, a3 = {0.f,0.f};
    int k = rs;
    for (; k + 8 <= re; k += 8) {  // 4 pairs = 8 edges / iter
        int2 e0 = csre[k],     e1 = csre[k + 1], e2 = csre[k + 2], e3 = csre[k + 3];
        int2 e4 = csre[k + 4], e5 = csre[k + 5], e6 = csre[k + 6], e7 = csre[k + 7];
        int   r0 = half ? e1.x : e0.x;  float w0 = __int_as_float(half ? e1.y : e0.y);
        int   r1 = half ? e3.x : e2.x;  float w1 = __int_as_float(half ? e3.y : e2.y);
        int   r2 = half ? e5.x : e4.x;  float w2 = __int_as_float(half ? e5.y : e4.y);
        int   r3 = half ? e7.x : e6.x;  float w3 = __int_as_float(half ? e7.y : e6.y);
        unsigned u0 = xb32[(size_t)r0 * 32 + l5];
        unsigned u1 = xb32[(size_t)r1 * 32 + l5];
        unsigned u2 = xb32[(size_t)r2 * 32 + l5];
        unsigned u3 = xb32[(size_t)r3 * 32 + l5];
        a0.x += w0 * bflo(u0); a0.y += w0 * bfhi(u0);
        a1.x += w1 * bflo(u1); a1.y += w1 * bfhi(u1);
        a2.x += w2 * bflo(u2); a2.y += w2 * bfhi(u2);
        a3.x += w3 * bflo(u3); a3.y += w3 * bfhi(u3);
    }
    for (; k + 2 <= re; k += 2) {
        int2 e0 = csre[k], e1 = csre[k + 1];
        int r0 = half ? e1.x : e0.x;  float w0 = __int_as_float(half ? e1.y : e0.y);
        unsigned u0 = xb32[(size_t)r0 * 32 + l5];
        a0.x += w0 * bflo(u0); a0.y += w0 * bfhi(u0);
    }
    if (k < re) {
        int2 e0 = csre[k];
        float w0 = half ? 0.0f : __int_as_float(e0.y);
        unsigned u0 = xb32[(size_t)e0.x * 32 + l5];
        a0.x += w0 * bflo(u0); a0.y += w0 * bfhi(u0);
    }
    float sx = a0.x + a1.x + a2.x + a3.x;
    float sy = a0.y + a1.y + a2.y + a3.y;
    sx += __shfl_xor(sx, 32);
    sy += __shfl_xor(sy, 32);
    if (half == 0) {
        float d = dinv[node];
        float dd = d * d;
        unsigned us = xb32[(size_t)node * 32 + l5];
        zs[wv][2 * l5]     = sx + dd * bflo(us);
        zs[wv][2 * l5 + 1] = sy + dd * bfhi(us);
    }
    __syncthreads();
    // GEMM phase: all 512 threads; j = t&127, group g handles rows 2g, 2g+1
    {
        int j = t & 127;
        int g = t >> 7;  // 0..3
        float acc0 = 0.f, acc1 = 0.f;
        for (int kk = 0; kk < 64; kk++) {
            float wk = W[kk * 128 + j];
            acc0 += zs[2 * g][kk] * wk;
            acc1 += zs[2 * g + 1][kk] * wk;
        }
        float b = bias[j];
        size_t row0 = (size_t)blockIdx.x * 8 + 2 * g;
        float v0 = fmaxf(acc0 + b, 0.0f);
        float v1 = fmaxf(acc1 + b, 0.0f);
        __hip_bfloat16 h0 = __float2bfloat16(v0);
        __hip_bfloat16 h1 = __float2bfloat16(v1);
        C[row0 * 128 + j]       = *(ushort*)&h0;
        C[(row0 + 1) * 128 + j] = *(ushort*)&h1;
    }
}

// ---- gather2: edge-pair half-wave (uint2 = 4ch/lane) + fused mean-pool ----

__global__ __launch_bounds__(512) void k_gather2(const int2* __restrict__ csre,
                                                 const int* __restrict__ row_start,
                                                 const float* __restrict__ dinv,
                                                 const uint2* __restrict__ h2,
                                                 const int* __restrict__ batch,
                                                 float* __restrict__ gsum2) {
    __shared__ float4 red[8][32];
    int t = threadIdx.x;
    int wv = t >> 6;
    int lane = t & 63;
    int half = lane >> 5;
    int l5 = lane & 31;
    int node = blockIdx.x * 8 + wv;
    int rs = row_start[node];
    int re = (node == N_NODES - 1) ? N_EDGES : row_start[node + 1];
    float4 a0 = {0,0,0,0}, a1 = {0,0,0,0}, a2 = {0,0,0,0}, a3 = {0,0,0,0};
#define FMA4(acc_, w_, u_) { acc_.x += (w_) * bflo((u_).x); acc_.y += (w_) * bfhi((u_).x); \
                             acc_.z += (w_) * bflo((u_).y); acc_.w += (w_) * bfhi((u_).y); }
    int k = rs;
    for (; k + 8 <= re; k += 8) {
        int2 e0 = csre[k],     e1 = csre[k + 1], e2 = csre[k + 2], e3 = csre[k + 3];
        int2 e4 = csre[k + 4], e5 = csre[k + 5], e6 = csre[k + 6], e7 = csre[k + 7];
        int   r0 = half ? e1.x : e0.x;  float w0 = __int_as_float(half ? e1.y : e0.y);
        int   r1 = half ? e3.x : e2.x;  float w1 = __int_as_float(half ? e3.y : e2.y);
        int   r2 = half ? e5.x : e4.x;  float w2 = __int_as_float(half ? e5.y : e4.y);
        int   r3 = half ? e7.x : e6.x;  float w3 = __int_as_float(half ? e7.y : e6.y);
        uint2 u0 = h2[(size_t)r0 * 32 + l5];
        uint2 u1 = h2[(size_t)r1 * 32 + l5];
        uint2 u2 = h2[(size_t)r2 * 32 + l5];
        uint2 u3 = h2[(size_t)r3 * 32 + l5];
        FMA4(a0, w0, u0); FMA4(a1, w1, u1); FMA4(a2, w2, u2); FMA4(a3, w3, u3);
    }
    for (; k + 2 <= re; k += 2) {
        int2 e0 = csre[k], e1 = csre[k + 1];
        int r0 = half ? e1.x : e0.x;  float w0 = __int_as_float(half ? e1.y : e0.y);
        uint2 u0 = h2[(size_t)r0 * 32 + l5];
        FMA4(a0, w0, u0);
    }
    if (k < re) {
        int2 e0 = csre[k];
        float w0 = half ? 0.0f : __int_as_float(e0.y);
        uint2 u0 = h2[(size_t)e0.x * 32 + l5];
        FMA4(a0, w0, u0);
    }
#undef FMA4
    float4 s;
    s.x = a0.x + a1.x + a2.x + a3.x;
    s.y = a0.y + a1.y + a2.y + a3.y;
    s.z = a0.z + a1.z + a2.z + a3.z;
    s.w = a0.w + a1.w + a2.w + a3.w;
    s.x += __shfl_xor(s.x, 32);
    s.y += __shfl_xor(s.y, 32);
    s.z += __shfl_xor(s.z, 32);
    s.w += __shfl_xor(s.w, 32);
    float4 r;
    if (half == 0) {
        float d = dinv[node];
        float dd = d * d;
        uint2 us = h2[(size_t)node * 32 + l5];
        r.x = s.x + dd * bflo(us.x);
        r.y = s.y + dd * bfhi(us.x);
        r.z = s.z + dd * bflo(us.y);
        r.w = s.w + dd * bfhi(us.y);
        red[wv][l5] = r;
    }
    __syncthreads();
    int base8 = blockIdx.x * 8;
    int g0 = batch[base8];
    int g7 = batch[base8 + 7];
    if (g0 == g7) {
        if (t < 32) {
            float4 acc = {0,0,0,0};
#pragma unroll
            for (int q = 0; q < 8; q++) {
                float4 v = red[q][t];
                acc.x += v.x; acc.y += v.y; acc.z += v.z; acc.w += v.w;
            }
            atomicAdd(&gsum2[g0 * 128 + t * 4 + 0], acc.x);
            atomicAdd(&gsum2[g0 * 128 + t * 4 + 1], acc.y);
            atomicAdd(&gsum2[g0 * 128 + t * 4 + 2], acc.z);
            atomicAdd(&gsum2[g0 * 128 + t * 4 + 3], acc.w);
        }
    } else if (half == 0) {
        int g = batch[node];
        atomicAdd(&gsum2[g * 128 + l5 * 4 + 0], r.x);
        atomicAdd(&gsum2[g * 128 + l5 * 4 + 1], r.y);
        atomicAdd(&gsum2[g * 128 + l5 * 4 + 2], r.z);
        atomicAdd(&gsum2[g * 128 + l5 * 4 + 3], r.w);
    }
}

// ---------------- final: gcnt (binary search) + z = mean2 @ W2 + b2 ; MLP ----------------

__global__ __launch_bounds__(128) void k_mlp(const float* __restrict__ gsum2,
                                             const float* __restrict__ gt_sum,
                                             const int* __restrict__ batch,
                                             const float* __restrict__ W2,
                                             const float* __restrict__ b2,
                                             const float* __restrict__ Wm1,
                                             const float* __restrict__ bm1,
                                             const float* __restrict__ Wm2,
                                             const float* __restrict__ bm2,
                                             float* __restrict__ out) {
    __shared__ float srow[HIDDEN];
    __shared__ float g144[HIDDEN + GRAPH_DIM];
    __shared__ float sm[HIDDEN];
    __shared__ int cnt_sh;
    int b = blockIdx.x;
    int j = threadIdx.x;  // 0..127
    float raw = gsum2[b * 128 + j];
    float gtraw = (j < GRAPH_DIM) ? gt_sum[b * GRAPH_DIM + j] : 0.0f;
    if (j == 0) {
        int lo = 0, hi = N_NODES;
        while (lo < hi) { int m = (lo + hi) >> 1; if (batch[m] < b) lo = m + 1; else hi = m; }
        int a = lo;
        lo = 0; hi = N_NODES;
        while (lo < hi) { int m = (lo + hi) >> 1; if (batch[m] < b + 1) lo = m + 1; else hi = m; }
        cnt_sh = lo - a;
    }
    __syncthreads();
    float inv = 1.0f / fmaxf((float)cnt_sh, 1.0f);
    srow[j] = raw * inv;
    if (j < GRAPH_DIM) g144[128 + j] = gtraw * inv;
    __syncthreads();
    float z = b2[j];
    for (int k = 0; k < 128; k++) z += srow[k] * W2[k * 128 + j];
    g144[j] = z;
    __syncthreads();
    float acc = bm1[j];
    for (int k = 0; k < HIDDEN + GRAPH_DIM; k++) acc += g144[k] * Wm1[k * 128 + j];
    sm[j] = fmaxf(acc, 0.0f);
    __syncthreads();
    if (j < OUT_DIM) {
        float o = bm2[j];
        for (int k = 0; k < 128; k++) o += sm[k] * Wm2[k * OUT_DIM + j];
        out[b * OUT_DIM + j] = o;
    }
}

extern "C" void kernel_launch(void* const* d_in, const int* in_sizes, int n_in,
                              void* d_out, int out_size, void* d_ws, size_t ws_size,
                              hipStream_t stream) {
    const float* x    = (const float*)d_in[0];
    const int*   edge = (const int*)d_in[1];
    const int*   src  = edge;
    const int*   dst  = edge + N_EDGES;
    const int*   batch= (const int*)d_in[2];
    const float* W1   = (const float*)d_in[3];
    const float* b1   = (const float*)d_in[4];
    const float* W2   = (const float*)d_in[5];
    const float* b2   = (const float*)d_in[6];
    const float* Wm1  = (const float*)d_in[7];
    const float* bm1  = (const float*)d_in[8];
    const float* Wm2  = (const float*)d_in[9];
    const float* bm2  = (const float*)d_in[10];
    float* out = (float*)d_out;

    // workspace layout (~66 MB)
    char* ws = (char*)d_ws;
    char* p = ws;
    unsigned* bin   = (unsigned*)p;  p += (size_t)NBUCKETS * BIN_CAP * 4;   // 12.8 MB
    int2*  csre     = (int2*)p;      p += (size_t)N_EDGES * 8;              // 12.8 MB
    ushort* h1b     = (ushort*)p;    p += (size_t)N_NODES * 128 * 2;        // h1 bf16 25.6 MB
    ushort* xb      = (ushort*)p;    p += (size_t)N_NODES * 64 * 2;         // x bf16 12.8 MB
    int*   degcnt   = (int*)p;       p += (size_t)NBUCKETS * 256 * 4;
    int*   row_start= (int*)p;       p += (size_t)N_NODES * 4;
    float* dinv     = (float*)p;     p += (size_t)N_NODES * 4;
    int*   gcur     = (int*)p;       p += (size_t)NBUCKETS * 4;
    int*   bsum     = (int*)p;       p += 512 * 4;
    int*   bofs     = (int*)p;       p += 512 * 4;
    float* gt_sum   = (float*)p;     p += (size_t)N_GRAPHS * GRAPH_DIM * 4;
    float* gsum2    = (float*)p;     p += (size_t)N_GRAPHS * 128 * 4;

    hipMemsetAsync(gcur, 0, (size_t)NBUCKETS * 4, stream);

    // CSR build
    k_binplace<<<(N_EDGES + EPB - 1) / EPB, 256, 0, stream>>>(src, dst, gcur, bin);
    k_degBf<<<NBUCKETS, 256, 0, stream>>>(gcur, bin, degcnt, dinv, bsum);
    k_scanb<<<1, 512, 0, stream>>>(bsum, bofs);
    k_rowfill<<<NBUCKETS, 256, 0, stream>>>(degcnt, bofs, gcur, bin, dinv, row_start, csre, gt_sum);

    // bf16 pack + graph stats
    k_packstat<<<(N_NODES + 63) / 64, 256, 0, stream>>>(x, batch, xb, gt_sum);

    // conv1 fused: z1 = A_hat * x64 (LDS) ; h1 = relu(z1 @ W1 + b1) (bf16)
    k_conv1<<<N_NODES / 8, 512, 0, stream>>>(csre, row_start, dinv, (const unsigned*)xb,
                                             W1, b1, h1b, gsum2);

    // conv2 pooled: gsum2[g] = sum_{node in g} (A_hat h1)[node]
    k_gather2<<<N_NODES / 8, 512, 0, stream>>>(csre, row_start, dinv,
                                               (const uint2*)h1b, batch, gsum2);

    // final: gcnt + z = (gsum2/cnt) @ W2 + b2 ; MLP
    k_mlp<<<N_GRAPHS, 128, 0, stream>>>(gsum2, gt_sum, batch, W2, b2, Wm1, bm1, Wm2, bm2, out);
}

// Round 9
// 290.465 us; speedup vs baseline: 1.0359x; 1.0359x over previous
//
#include <hip/hip_runtime.h>
#include <hip/hip_bf16.h>

#define N_NODES 100000
#define N_EDGES 1600000
#define N_GRAPHS 512
#define NODE_DIM 64
#define GRAPH_DIM 16
#define HIDDEN 128
#define OUT_DIM 8

#define NBUCKETS 782      // ceil(N_NODES/128)
#define BNODES 128        // nodes per bucket
#define BIN_CAP 4096      // per-bucket bin capacity (avg 2046)
#define EPB 4096          // edges per binning block

__device__ __forceinline__ float bflo(unsigned u) { return __uint_as_float(u << 16); }
__device__ __forceinline__ float bfhi(unsigned u) { return __uint_as_float(u & 0xffff0000u); }

// ---------------- phase A: bin edges by dst>>7; entry = (src<<7)|(dst&127) ----------------

__global__ __launch_bounds__(256) void k_binplace(const int* __restrict__ src,
                                                  const int* __restrict__ dst,
                                                  int* __restrict__ gcur,
                                                  unsigned* __restrict__ bin) {
    __shared__ int cnt[NBUCKETS];
    __shared__ int base[NBUCKETS];
    int t = threadIdx.x;
    for (int i = t; i < NBUCKETS; i += 256) cnt[i] = 0;
    __syncthreads();
    int e0 = blockIdx.x * EPB;
#pragma unroll
    for (int k = 0; k < EPB / 256; k++) {
        int e = e0 + k * 256 + t;
        if (e < N_EDGES) atomicAdd(&cnt[dst[e] >> 7], 1);
    }
    __syncthreads();
    for (int i = t; i < NBUCKETS; i += 256) {
        int c = cnt[i];
        base[i] = (c > 0) ? atomicAdd(&gcur[i], c) : 0;
        cnt[i] = 0;
    }
    __syncthreads();
#pragma unroll
    for (int k = 0; k < EPB / 256; k++) {
        int e = e0 + k * 256 + t;
        if (e < N_EDGES) {
            int d = dst[e];
            int b = d >> 7;
            int p = atomicAdd(&cnt[b], 1);
            bin[(size_t)b * BIN_CAP + base[b] + p] = ((unsigned)src[e] << 7) | (unsigned)(d & 127);
        }
    }
}

// ---------------- phase B1: per-bucket degree count + dinv; block 0 scans gcur -> bofs ----------------

__global__ __launch_bounds__(256) void k_degscan(const int* __restrict__ gcur,
                                                 const unsigned* __restrict__ bin,
                                                 int* __restrict__ degcnt,
                                                 float* __restrict__ dinv,
                                                 int* __restrict__ bofs) {
    __shared__ int cnt[BNODES];
    int b = blockIdx.x, t = threadIdx.x;
    if (t < BNODES) cnt[t] = 0;
    __syncthreads();
    int n = gcur[b];
    const unsigned* seg = bin + (size_t)b * BIN_CAP;
    for (int i = t; i < n; i += 256) atomicAdd(&cnt[seg[i] & 127u], 1);
    __syncthreads();
    int node = b * BNODES + t;
    if (t < BNODES && node < N_NODES) {
        int c = cnt[t];
        degcnt[node] = c;
        dinv[node] = rsqrtf((float)c + 1.0f);
    }
    if (b == 0) {
        // exclusive scan of gcur[0..NBUCKETS-1] -> bofs, 4 elems/thread
        __shared__ int ls[256];
        int i0 = 4 * t;
        int c0 = (i0 + 0 < NBUCKETS) ? gcur[i0 + 0] : 0;
        int c1 = (i0 + 1 < NBUCKETS) ? gcur[i0 + 1] : 0;
        int c2 = (i0 + 2 < NBUCKETS) ? gcur[i0 + 2] : 0;
        int c3 = (i0 + 3 < NBUCKETS) ? gcur[i0 + 3] : 0;
        int s = c0 + c1 + c2 + c3;
        ls[t] = s;
        __syncthreads();
        for (int o = 1; o < 256; o <<= 1) {
            int u = (t >= o) ? ls[t - o] : 0;
            __syncthreads();
            ls[t] += u;
            __syncthreads();
        }
        int run = ls[t] - s;
        if (i0 + 0 < NBUCKETS) bofs[i0 + 0] = run; run += c0;
        if (i0 + 1 < NBUCKETS) bofs[i0 + 1] = run; run += c1;
        if (i0 + 2 < NBUCKETS) bofs[i0 + 2] = run; run += c2;
        if (i0 + 3 < NBUCKETS) bofs[i0 + 3] = run;
    }
}

// ---------------- phase B2: rowstart + CSR fill (int2 {src, w}); zeroes gt_sum; pads csre ----------------

__global__ __launch_bounds__(256) void k_rowfill(const int* __restrict__ degcnt,
                                                 const int* __restrict__ bofs,
                                                 const int* __restrict__ gcur,
                                                 const unsigned* __restrict__ bin,
                                                 const float* __restrict__ dinv,
                                                 int* __restrict__ row_start,
                                                 int2* __restrict__ csre,
                                                 float* __restrict__ gt_sum) {
    __shared__ int sc[BNODES];
    __shared__ int rsl[BNODES];
    __shared__ int cnt[BNODES];
    __shared__ float dl[BNODES];
    int b = blockIdx.x, t = threadIdx.x;
    if (b < 32) gt_sum[b * 256 + t] = 0.0f;
    int node = b * BNODES + t;
    int v = 0;
    if (t < BNODES) {
        v = (node < N_NODES) ? degcnt[node] : 0;
        sc[t] = v;
    }
    __syncthreads();
    for (int o = 1; o < BNODES; o <<= 1) {
        int u = 0;
        if (t < BNODES && t >= o) u = sc[t - o];
        __syncthreads();
        if (t < BNODES) sc[t] += u;
        __syncthreads();
    }
    if (t < BNODES) {
        int rs = bofs[b] + sc[t] - v;  // exclusive
        if (node < N_NODES) row_start[node] = rs;
        rsl[t] = rs;
        cnt[t] = 0;
        dl[t] = rsqrtf((float)v + 1.0f);
    }
    __syncthreads();
    int n = gcur[b];
    const unsigned* seg = bin + (size_t)b * BIN_CAP;
    for (int i = t; i < n; i += 256) {
        unsigned e = seg[i];
        int dlidx = (int)(e & 127u);
        int s = (int)(e >> 7);
        int pos = rsl[dlidx] + atomicAdd(&cnt[dlidx], 1);
        csre[pos] = make_int2(s, __float_as_int(dinv[s] * dl[dlidx]));
    }
    if (b == NBUCKETS - 1) {
        if (t < 8) csre[N_EDGES + t] = make_int2(0, 0);   // pad for masked unroll-8
        if (t == 8) row_start[N_NODES] = N_EDGES;
    }
}

// ---------------- fused: pack x[:, :64] to bf16 + graph feature pooling ----------------

__global__ __launch_bounds__(256) void k_packstat(const float* __restrict__ x,
                                                  const int* __restrict__ batch,
                                                  ushort* __restrict__ xb,
                                                  float* __restrict__ gt_sum) {
    int t = threadIdx.x;
    int i0 = blockIdx.x * 64;
    for (int idx = t; idx < 64 * 32; idx += 256) {
        int node = i0 + (idx >> 5);
        if (node < N_NODES) {
            int c2 = idx & 31;
            float2 v = *(const float2*)&x[(size_t)node * 80 + c2 * 2];
            __hip_bfloat16 lo = __float2bfloat16(v.x);
            __hip_bfloat16 hi = __float2bfloat16(v.y);
            ushort2 pv = make_ushort2(*(ushort*)&lo, *(ushort*)&hi);
            ((ushort2*)xb)[(size_t)node * 32 + c2] = pv;
        }
    }
    int c = t & 15, sub = t >> 4;  // 16 subs x 16 channels
    int iend = min(i0 + 64, N_NODES);
    float acc = 0.0f;
    int g = -1;
    for (int i = i0 + sub; i < iend; i += 16) {
        int bi = batch[i];
        if (bi != g) {
            if (g >= 0) atomicAdd(&gt_sum[g * GRAPH_DIM + c], acc);
            acc = 0.0f; g = bi;
        }
        acc += x[(size_t)i * 80 + NODE_DIM + c];
    }
    if (g >= 0) atomicAdd(&gt_sum[g * GRAPH_DIM + c], acc);
}

// ---- fused conv1: masked unroll-8 gather (whole-wave, 2 nodes/wave) + GEMM; zeroes gsum2 ----

#define LDX(s_) __uint_as_float((unsigned)xb[(size_t)(s_)*64 + lane] << 16)

__global__ __launch_bounds__(256) void k_conv1(const int2* __restrict__ csre,
                                               const int* __restrict__ row_start,
                                               const float* __restrict__ dinv,
                                               const ushort* __restrict__ xb,
                                               const float* __restrict__ W,
                                               const float* __restrict__ bias,
                                               ushort* __restrict__ C,
                                               float* __restrict__ gsum2) {
    __shared__ float zs[8][64];
    int t = threadIdx.x;
    if (blockIdx.x < 256) gsum2[blockIdx.x * 256 + t] = 0.0f;
    int wv = t >> 6, lane = t & 63;
    int nA = blockIdx.x * 8 + wv * 2;
    int nB = nA + 1;
    int kA = row_start[nA], reA = row_start[nA + 1];
    int kB = reA,           reB = row_start[nB + 1];
    float aA0 = 0.f, aA1 = 0.f, aA2 = 0.f, aA3 = 0.f;
    float aB0 = 0.f, aB1 = 0.f, aB2 = 0.f, aB3 = 0.f;
    while (kA < reA || kB < reB) {
        if (kA < reA) {
            int2 e0 = csre[kA],     e1 = csre[kA + 1], e2 = csre[kA + 2], e3 = csre[kA + 3];
            int2 e4 = csre[kA + 4], e5 = csre[kA + 5], e6 = csre[kA + 6], e7 = csre[kA + 7];
            float w0 = (kA + 0 < reA) ? __int_as_float(e0.y) : 0.f;
            float w1 = (kA + 1 < reA) ? __int_as_float(e1.y) : 0.f;
            float w2 = (kA + 2 < reA) ? __int_as_float(e2.y) : 0.f;
            float w3 = (kA + 3 < reA) ? __int_as_float(e3.y) : 0.f;
            float w4 = (kA + 4 < reA) ? __int_as_float(e4.y) : 0.f;
            float w5 = (kA + 5 < reA) ? __int_as_float(e5.y) : 0.f;
            float w6 = (kA + 6 < reA) ? __int_as_float(e6.y) : 0.f;
            float w7 = (kA + 7 < reA) ? __int_as_float(e7.y) : 0.f;
            float v0 = LDX(e0.x), v1 = LDX(e1.x), v2 = LDX(e2.x), v3 = LDX(e3.x);
            float v4 = LDX(e4.x), v5 = LDX(e5.x), v6 = LDX(e6.x), v7 = LDX(e7.x);
            aA0 += w0 * v0; aA1 += w1 * v1; aA2 += w2 * v2; aA3 += w3 * v3;
            aA0 += w4 * v4; aA1 += w5 * v5; aA2 += w6 * v6; aA3 += w7 * v7;
            kA += 8;
        }
        if (kB < reB) {
            int2 e0 = csre[kB],     e1 = csre[kB + 1], e2 = csre[kB + 2], e3 = csre[kB + 3];
            int2 e4 = csre[kB + 4], e5 = csre[kB + 5], e6 = csre[kB + 6], e7 = csre[kB + 7];
            float w0 = (kB + 0 < reB) ? __int_as_float(e0.y) : 0.f;
            float w1 = (kB + 1 < reB) ? __int_as_float(e1.y) : 0.f;
            float w2 = (kB + 2 < reB) ? __int_as_float(e2.y) : 0.f;
            float w3 = (kB + 3 < reB) ? __int_as_float(e3.y) : 0.f;
            float w4 = (kB + 4 < reB) ? __int_as_float(e4.y) : 0.f;
            float w5 = (kB + 5 < reB) ? __int_as_float(e5.y) : 0.f;
            float w6 = (kB + 6 < reB) ? __int_as_float(e6.y) : 0.f;
            float w7 = (kB + 7 < reB) ? __int_as_float(e7.y) : 0.f;
            float v0 = LDX(e0.x), v1 = LDX(e1.x), v2 = LDX(e2.x), v3 = LDX(e3.x);
            float v4 = LDX(e4.x), v5 = LDX(e5.x), v6 = LDX(e6.x), v7 = LDX(e7.x);
            aB0 += w0 * v0; aB1 += w1 * v1; aB2 += w2 * v2; aB3 += w3 * v3;
            aB0 += w4 * v4; aB1 += w5 * v5; aB2 += w6 * v6; aB3 += w7 * v7;
            kB += 8;
        }
    }
    float dA = dinv[nA], dB = dinv[nB];
    zs[wv * 2][lane]     = aA0 + aA1 + aA2 + aA3 + dA * dA * LDX(nA);
    zs[wv * 2 + 1][lane] = aB0 + aB1 + aB2 + aB3 + dB * dB * LDX(nB);
    __syncthreads();
    // GEMM phase: threads 0..127, 8 rows from LDS
    if (t < 128) {
        int j = t;
        float acc[8];
#pragma unroll
        for (int m = 0; m < 8; m++) acc[m] = 0.0f;
        for (int k = 0; k < 64; k++) {
            float wv2 = W[k * 128 + j];
#pragma unroll
            for (int m = 0; m < 8; m++) acc[m] += zs[m][k] * wv2;
        }
        float b = bias[j];
        size_t row0 = (size_t)blockIdx.x * 8;
#pragma unroll
        for (int m = 0; m < 8; m++) {
            float v = fmaxf(acc[m] + b, 0.0f);
            __hip_bfloat16 hv = __float2bfloat16(v);
            C[(row0 + m) * 128 + j] = *(ushort*)&hv;
        }
    }
}

// ---- gather2: masked unroll-8 (whole-wave, 2 nodes/wave, 2ch/lane) + fused mean-pool ----

__global__ __launch_bounds__(256) void k_gather2(const int2* __restrict__ csre,
                                                 const int* __restrict__ row_start,
                                                 const float* __restrict__ dinv,
                                                 const unsigned* __restrict__ h,
                                                 const int* __restrict__ batch,
                                                 float* __restrict__ gsum2) {
    __shared__ float2 red[8][64];
    int w = threadIdx.x >> 6, lane = threadIdx.x & 63;
    int nA = blockIdx.x * 8 + w * 2;
    int nB = nA + 1;
    int kA = row_start[nA], reA = row_start[nA + 1];
    int kB = reA,           reB = row_start[nB + 1];
    float2 aA0 = {0.f,0.f}, aA1 = {0.f,0.f}, aA2 = {0.f,0.f}, aA3 = {0.f,0.f};
    float2 aB0 = {0.f,0.f}, aB1 = {0.f,0.f}, aB2 = {0.f,0.f}, aB3 = {0.f,0.f};
#define FMA2(acc_, w_, u_) { acc_.x += (w_) * bflo(u_); acc_.y += (w_) * bfhi(u_); }
    while (kA < reA || kB < reB) {
        if (kA < reA) {
            int2 e0 = csre[kA],     e1 = csre[kA + 1], e2 = csre[kA + 2], e3 = csre[kA + 3];
            int2 e4 = csre[kA + 4], e5 = csre[kA + 5], e6 = csre[kA + 6], e7 = csre[kA + 7];
            float w0 = (kA + 0 < reA) ? __int_as_float(e0.y) : 0.f;
            float w1 = (kA + 1 < reA) ? __int_as_float(e1.y) : 0.f;
            float w2 = (kA + 2 < reA) ? __int_as_float(e2.y) : 0.f;
            float w3 = (kA + 3 < reA) ? __int_as_float(e3.y) : 0.f;
            float w4 = (kA + 4 < reA) ? __int_as_float(e4.y) : 0.f;
            float w5 = (kA + 5 < reA) ? __int_as_float(e5.y) : 0.f;
            float w6 = (kA + 6 < reA) ? __int_as_float(e6.y) : 0.f;
            float w7 = (kA + 7 < reA) ? __int_as_float(e7.y) : 0.f;
            unsigned u0 = h[(size_t)e0.x * 64 + lane], u1 = h[(size_t)e1.x * 64 + lane];
            unsigned u2 = h[(size_t)e2.x * 64 + lane], u3 = h[(size_t)e3.x * 64 + lane];
            unsigned u4 = h[(size_t)e4.x * 64 + lane], u5 = h[(size_t)e5.x * 64 + lane];
            unsigned u6 = h[(size_t)e6.x * 64 + lane], u7 = h[(size_t)e7.x * 64 + lane];
            FMA2(aA0, w0, u0); FMA2(aA1, w1, u1); FMA2(aA2, w2, u2); FMA2(aA3, w3, u3);
            FMA2(aA0, w4, u4); FMA2(aA1, w5, u5); FMA2(aA2, w6, u6); FMA2(aA3, w7, u7);
            kA += 8;
        }
        if (kB < reB) {
            int2 e0 = csre[kB],     e1 = csre[kB + 1], e2 = csre[kB + 2], e3 = csre[kB + 3];
            int2 e4 = csre[kB + 4], e5 = csre[kB + 5], e6 = csre[kB + 6], e7 = csre[kB + 7];
            float w0 = (kB + 0 < reB) ? __int_as_float(e0.y) : 0.f;
            float w1 = (kB + 1 < reB) ? __int_as_float(e1.y) : 0.f;
            float w2 = (kB + 2 < reB) ? __int_as_float(e2.y) : 0.f;
            float w3 = (kB + 3 < reB) ? __int_as_float(e3.y) : 0.f;
            float w4 = (kB + 4 < reB) ? __int_as_float(e4.y) : 0.f;
            float w5 = (kB + 5 < reB) ? __int_as_float(e5.y) : 0.f;
            float w6 = (kB + 6 < reB) ? __int_as_float(e6.y) : 0.f;
            float w7 = (kB + 7 < reB) ? __int_as_float(e7.y) : 0.f;
            unsigned u0 = h[(size_t)e0.x * 64 + lane], u1 = h[(size_t)e1.x * 64 + lane];
            unsigned u2 = h[(size_t)e2.x * 64 + lane], u3 = h[(size_t)e3.x * 64 + lane];
            unsigned u4 = h[(size_t)e4.x * 64 + lane], u5 = h[(size_t)e5.x * 64 + lane];
            unsigned u6 = h[(size_t)e6.x * 64 + lane], u7 = h[(size_t)e7.x * 64 + lane];
            FMA2(aB0, w0, u0); FMA2(aB1, w1, u1); FMA2(aB2, w2, u2); FMA2(aB3, w3, u3);
            FMA2(aB0, w4, u4); FMA2(aB1, w5, u5); FMA2(aB2, w6, u6); FMA2(aB3, w7, u7);
            kB += 8;
        }
    }
#undef FMA2
    float dA = dinv[nA], dB = dinv[nB];
    unsigned usA = h[(size_t)nA * 64 + lane];
    unsigned usB = h[(size_t)nB * 64 + lane];
    float2 rA, rB;
    rA.x = aA0.x + aA1.x + aA2.x + aA3.x + dA * dA * bflo(usA);
    rA.y = aA0.y + aA1.y + aA2.y + aA3.y + dA * dA * bfhi(usA);
    rB.x = aB0.x + aB1.x + aB2.x + aB3.x + dB * dB * bflo(usB);
    rB.y = aB0.y + aB1.y + aB2.y + aB3.y + dB * dB * bfhi(usB);
    red[w * 2][lane] = rA;
    red[w * 2 + 1][lane] = rB;
    __syncthreads();
    int g0 = batch[blockIdx.x * 8];
    int g7 = batch[blockIdx.x * 8 + 7];
    if (g0 == g7) {
        if (w == 0) {
            float sx = 0.f, sy = 0.f;
#pragma unroll
            for (int q = 0; q < 8; q++) { sx += red[q][lane].x; sy += red[q][lane].y; }
            atomicAdd(&gsum2[g0 * 128 + 2 * lane], sx);
            atomicAdd(&gsum2[g0 * 128 + 2 * lane + 1], sy);
        }
    } else {
        int gA = batch[nA], gB = batch[nB];
        atomicAdd(&gsum2[gA * 128 + 2 * lane], rA.x);
        atomicAdd(&gsum2[gA * 128 + 2 * lane + 1], rA.y);
        atomicAdd(&gsum2[gB * 128 + 2 * lane], rB.x);
        atomicAdd(&gsum2[gB * 128 + 2 * lane + 1], rB.y);
    }
}

// ---------------- final: gcnt (binary search) + z = mean2 @ W2 + b2 ; MLP ----------------

__global__ __launch_bounds__(128) void k_mlp(const float* __restrict__ gsum2,
                                             const float* __restrict__ gt_sum,
                                             const int* __restrict__ batch,
                                             const float* __restrict__ W2,
                                             const float* __restrict__ b2,
                                             const float* __restrict__ Wm1,
                                             const float* __restrict__ bm1,
                                             const float* __restrict__ Wm2,
                                             const float* __restrict__ bm2,
                                             float* __restrict__ out) {
    __shared__ float srow[HIDDEN];
    __shared__ float g144[HIDDEN + GRAPH_DIM];
    __shared__ float sm[HIDDEN];
    __shared__ int cnt_sh;
    int b = blockIdx.x;
    int j = threadIdx.x;  // 0..127
    float raw = gsum2[b * 128 + j];
    float gtraw = (j < GRAPH_DIM) ? gt_sum[b * GRAPH_DIM + j] : 0.0f;
    if (j == 0) {
        int lo = 0, hi = N_NODES;
        while (lo < hi) { int m = (lo + hi) >> 1; if (batch[m] < b) lo = m + 1; else hi = m; }
        int a = lo;
        lo = 0; hi = N_NODES;
        while (lo < hi) { int m = (lo + hi) >> 1; if (batch[m] < b + 1) lo = m + 1; else hi = m; }
        cnt_sh = lo - a;
    }
    __syncthreads();
    float inv = 1.0f / fmaxf((float)cnt_sh, 1.0f);
    srow[j] = raw * inv;
    if (j < GRAPH_DIM) g144[128 + j] = gtraw * inv;
    __syncthreads();
    float z = b2[j];
    for (int k = 0; k < 128; k++) z += srow[k] * W2[k * 128 + j];
    g144[j] = z;
    __syncthreads();
    float acc = bm1[j];
    for (int k = 0; k < HIDDEN + GRAPH_DIM; k++) acc += g144[k] * Wm1[k * 128 + j];
    sm[j] = fmaxf(acc, 0.0f);
    __syncthreads();
    if (j < OUT_DIM) {
        float o = bm2[j];
        for (int k = 0; k < 128; k++) o += sm[k] * Wm2[k * OUT_DIM + j];
        out[b * OUT_DIM + j] = o;
    }
}

extern "C" void kernel_launch(void* const* d_in, const int* in_sizes, int n_in,
                              void* d_out, int out_size, void* d_ws, size_t ws_size,
                              hipStream_t stream) {
    const float* x    = (const float*)d_in[0];
    const int*   edge = (const int*)d_in[1];
    const int*   src  = edge;
    const int*   dst  = edge + N_EDGES;
    const int*   batch= (const int*)d_in[2];
    const float* W1   = (const float*)d_in[3];
    const float* b1   = (const float*)d_in[4];
    const float* W2   = (const float*)d_in[5];
    const float* b2   = (const float*)d_in[6];
    const float* Wm1  = (const float*)d_in[7];
    const float* bm1  = (const float*)d_in[8];
    const float* Wm2  = (const float*)d_in[9];
    const float* bm2  = (const float*)d_in[10];
    float* out = (float*)d_out;

    // workspace layout (~66 MB)
    char* ws = (char*)d_ws;
    char* p = ws;
    unsigned* bin   = (unsigned*)p;  p += (size_t)NBUCKETS * BIN_CAP * 4;   // 12.8 MB
    int2*  csre     = (int2*)p;      p += ((size_t)N_EDGES + 8) * 8;        // 12.8 MB (+pad)
    ushort* h1b     = (ushort*)p;    p += (size_t)N_NODES * 128 * 2;        // h1 bf16 25.6 MB
    ushort* xb      = (ushort*)p;    p += (size_t)N_NODES * 64 * 2;         // x bf16 12.8 MB
    int*   degcnt   = (int*)p;       p += (size_t)NBUCKETS * BNODES * 4;
    int*   row_start= (int*)p;       p += ((size_t)N_NODES + 1) * 4;
    float* dinv     = (float*)p;     p += (size_t)N_NODES * 4;
    int*   gcur     = (int*)p;       p += (size_t)NBUCKETS * 4;
    int*   bofs     = (int*)p;       p += (size_t)NBUCKETS * 4;
    float* gt_sum   = (float*)p;     p += (size_t)N_GRAPHS * GRAPH_DIM * 4;
    float* gsum2    = (float*)p;     p += (size_t)N_GRAPHS * 128 * 4;

    hipMemsetAsync(gcur, 0, (size_t)NBUCKETS * 4, stream);

    // CSR build
    k_binplace<<<(N_EDGES + EPB - 1) / EPB, 256, 0, stream>>>(src, dst, gcur, bin);
    k_degscan<<<NBUCKETS, 256, 0, stream>>>(gcur, bin, degcnt, dinv, bofs);
    k_rowfill<<<NBUCKETS, 256, 0, stream>>>(degcnt, bofs, gcur, bin, dinv, row_start, csre, gt_sum);

    // bf16 pack + graph stats
    k_packstat<<<(N_NODES + 63) / 64, 256, 0, stream>>>(x, batch, xb, gt_sum);

    // conv1 fused: z1 = A_hat * x64 (LDS) ; h1 = relu(z1 @ W1 + b1) (bf16)
    k_conv1<<<N_NODES / 8, 256, 0, stream>>>(csre, row_start, dinv, xb, W1, b1, h1b, gsum2);

    // conv2 pooled: gsum2[g] = sum_{node in g} (A_hat h1)[node]
    k_gather2<<<N_NODES / 8, 256, 0, stream>>>(csre, row_start, dinv,
                                               (const unsigned*)h1b, batch, gsum2);

    // final: gcnt + z = (gsum2/cnt) @ W2 + b2 ; MLP
    k_mlp<<<N_GRAPHS, 128, 0, stream>>>(gsum2, gt_sum, batch, W2, b2, Wm1, bm1, Wm2, bm2, out);
}